// Round 1
// baseline (230.997 us; speedup 1.0000x reference)
//
#include <hip/hip_runtime.h>
#include <math.h>

#define BB 4
#define NN 512
#define DD 256
#define LL 64

#define K1_NR 4      // x rows per block in projection kernel
#define WST  260     // 256 cols + 4 pad; 260 % 32 == 4 -> same conflict-free b128 pattern as 132
#define IPB  4       // i-rows per block in main kernel (512 blocks = 2/CU)

// ---------------------------------------------------------------------------
// k1: xhatT[b][l][n] = lw[l] * sum_d x[b][n][d] * W[l][d]
// lw is folded into W at stage time (valid: lw >= 0, and k2 only uses
// |xhat_i - xhat_j|, and w|a-b| == |wa - wb| for w >= 0 -- the previous
// passing kernel already relied on this identity).
// Full W staged ONCE per block via float4 loads + b128 LDS writes
// (17 staging insts/thread vs 128 scalar before), single __syncthreads.
// LDS: 66,560 + 4,096 B = 70.7 KB -> 2 blocks/CU.
// ---------------------------------------------------------------------------
__global__ __launch_bounds__(256) void k1_proj(const float* __restrict__ x,
                                               const float* __restrict__ Wp,
                                               const float* __restrict__ lw,
                                               float* __restrict__ xhatT) {
  __shared__ __align__(16) float Wl[LL * WST];    // 66,560 B, pre-scaled by lw
  __shared__ __align__(16) float xs[K1_NR * DD];  //  4,096 B
  const int bx = blockIdx.x;
  const int b  = bx >> 7;              // NN/K1_NR == 128
  const int n0 = (bx & 127) * K1_NR;
  const int t  = threadIdx.x;
  const int l  = t & 63;
  const int r  = t >> 6;

  // stage W pre-scaled: 4096 float4 / 256 threads = 16 iters, fully coalesced
  const float4* Wp4 = (const float4*)Wp;
  #pragma unroll
  for (int it = 0; it < 16; ++it) {
    int idx = it * 256 + t;
    int ll  = idx >> 6;                 // W row (wave-uniform per iteration)
    int dq  = idx & 63;                 // float4 column
    float4 wv = Wp4[idx];
    float  w  = lw[ll];                 // L1-resident broadcast
    wv.x *= w; wv.y *= w; wv.z *= w; wv.w *= w;
    *(float4*)&Wl[ll * WST + dq * 4] = wv;
  }
  // stage K1_NR rows of x: 256 float4, one per thread, coalesced
  ((float4*)xs)[t] = ((const float4*)x)[((size_t)(b * NN + n0)) * (DD / 4) + t];
  __syncthreads();

  const float4* xrow = (const float4*)&xs[r * DD];   // wave-uniform -> broadcast
  const float4* wrow = (const float4*)&Wl[l * WST];  // per-lane row, padded stride
  float4 a = make_float4(0.f, 0.f, 0.f, 0.f);
  #pragma unroll 8
  for (int dd = 0; dd < 64; ++dd) {
    float4 xv = xrow[dd];
    float4 wv = wrow[dd];
    a.x += xv.x * wv.x;
    a.y += xv.y * wv.y;
    a.z += xv.z * wv.z;
    a.w += xv.w * wv.w;
  }
  xhatT[(size_t)b * (LL * NN) + (size_t)l * NN + (n0 + r)] = (a.x + a.y) + (a.z + a.w);
}

// ---------------------------------------------------------------------------
// k2: per (b, i-tile of IPB): dist -> leaky_relu -> rowmax -> adj*exp ->
//     rowsum -> divide -> +1e-10.  512 threads, thread = column j.
// This round: the full xj column (64 values, already lw-scaled by k1) is
// preloaded into 64 VGPRs with back-to-back independent loads -- ONE
// pipelined L2 round-trip instead of 16 serialized vmcnt stalls.  The
// l-loop is then pure VALU + one b128 LDS broadcast.  Full unroll keeps
// xj[] statically indexed (runtime index -> scratch); the periodic empty-asm
// memory clobber bounds LDS-load hoisting to 8 iterations (32 floats) so
// registers stay under the 128/wave cap (4 waves/SIMD).
// ---------------------------------------------------------------------------
__global__ __launch_bounds__(512, 4) void k2_main(const float* __restrict__ xhatT,
                                                  const float* __restrict__ adj,
                                                  float* __restrict__ out) {
  __shared__ __align__(16) float xi_s[LL * IPB];  // [l][r], lw-scaled (from k1)
  __shared__ float redm[IPB * 8];
  __shared__ float reds[IPB * 8];

  const int bx   = blockIdx.x;
  const int b    = bx >> 7;             // NN/IPB == 128
  const int i0   = (bx & 127) * IPB;
  const int t    = threadIdx.x;         // j
  const int wave = t >> 6;
  const int lane = t & 63;

  const float* xb = xhatT + (size_t)b * (LL * NN);

  // preload full xj column: 64 independent coalesced dword loads (L2-resident)
  float xj[LL];
  #pragma unroll
  for (int l = 0; l < LL; ++l) xj[l] = xb[l * NN + t];

  // adj row loads issued early: cold-HBM latency hides under the l-loop
  const float* adjb = adj + ((size_t)b * NN + i0) * NN;
  float adjv[IPB];
  #pragma unroll
  for (int r = 0; r < IPB; ++r) adjv[r] = adjb[(size_t)r * NN + t];

  if (t < LL * IPB) {                   // 256 threads stage the xi tile
    int l = t >> 2, rr = t & 3;
    xi_s[t] = xb[l * NN + i0 + rr];
  }
  __syncthreads();

  float acc[IPB] = {0.f, 0.f, 0.f, 0.f};
  const float4* xi4 = (const float4*)xi_s;
  #pragma unroll
  for (int l = 0; l < LL; ++l) {
    float4 a = xi4[l];                  // broadcast b128
    float  p = xj[l];                   // register
    acc[0] += fabsf(a.x - p);
    acc[1] += fabsf(a.y - p);
    acc[2] += fabsf(a.z - p);
    acc[3] += fabsf(a.w - p);
    if ((l & 7) == 7) asm volatile("" ::: "memory");  // bound LDS prefetch depth
  }

  // leaky_relu (dist >= 0 in practice, but stay faithful)
  #pragma unroll
  for (int r = 0; r < IPB; ++r) {
    float d = acc[r];
    acc[r] = d >= 0.f ? d : 0.01f * d;
  }

  // row max over 512 j: wave shfl reduce, then cross-wave via LDS
  #pragma unroll
  for (int r = 0; r < IPB; ++r) {
    float m = acc[r];
    #pragma unroll
    for (int off = 32; off > 0; off >>= 1)
      m = fmaxf(m, __shfl_xor(m, off, 64));
    if (lane == 0) redm[r * 8 + wave] = m;
  }
  __syncthreads();

  float e[IPB];
  #pragma unroll
  for (int r = 0; r < IPB; ++r) {
    float m = redm[r * 8 + 0];
    #pragma unroll
    for (int k = 1; k < 8; ++k) m = fmaxf(m, redm[r * 8 + k]);  // broadcast reads
    e[r] = adjv[r] * __expf(acc[r] - m);
  }

  // row sum
  #pragma unroll
  for (int r = 0; r < IPB; ++r) {
    float s = e[r];
    #pragma unroll
    for (int off = 32; off > 0; off >>= 1)
      s += __shfl_xor(s, off, 64);
    if (lane == 0) reds[r * 8 + wave] = s;
  }
  __syncthreads();

  float* outb = out + ((size_t)b * NN + i0) * NN;
  #pragma unroll
  for (int r = 0; r < IPB; ++r) {
    float s = reds[r * 8 + 0];
    #pragma unroll
    for (int k = 1; k < 8; ++k) s += reds[r * 8 + k];
    outb[(size_t)r * NN + t] = e[r] / s + 1e-10f;   // epsilon AFTER division
  }
}

extern "C" void kernel_launch(void* const* d_in, const int* in_sizes, int n_in,
                              void* d_out, int out_size, void* d_ws, size_t ws_size,
                              hipStream_t stream) {
  const float* x   = (const float*)d_in[0];   // [B,N,D]
  const float* adj = (const float*)d_in[1];   // [B,N,N]
  const float* Wp  = (const float*)d_in[2];   // [L,D]
  const float* lw  = (const float*)d_in[3];   // [L]
  float* out   = (float*)d_out;               // [B,N,N]
  float* xhatT = (float*)d_ws;                // B*L*N floats = 512 KiB

  hipLaunchKernelGGL(k1_proj, dim3(BB * NN / K1_NR), dim3(256), 0, stream,
                     x, Wp, lw, xhatT);
  hipLaunchKernelGGL(k2_main, dim3(BB * NN / IPB), dim3(512), 0, stream,
                     xhatT, adj, out);
}

// Round 4
// 80.448 us; speedup vs baseline: 2.8714x; 2.8714x over previous
//
#include <hip/hip_runtime.h>
#include <math.h>

#define BB 4
#define NN 512
#define DD 256
#define LL 64

#define K1_NR 4      // x rows per block in projection kernel
#define WST  260     // 256 cols + 4 pad; 260 % 32 == 4 -> conflict-free b128 pattern
#define IPB  8       // i-rows per block in main kernel (256 blocks = 1/CU)

// ---------------------------------------------------------------------------
// k1: xhatT[b][l][n] = lw[l] * sum_d x[b][n][d] * W[l][d]
// lw folded into W at stage time (valid: lw >= 0, |w a - w b| == w|a-b|).
// Unchanged from round 1 (isolating the k2 fix); k1 cost gets measured this
// round now that k2 no longer swamps the top-5.
// ---------------------------------------------------------------------------
__global__ __launch_bounds__(256) void k1_proj(const float* __restrict__ x,
                                               const float* __restrict__ Wp,
                                               const float* __restrict__ lw,
                                               float* __restrict__ xhatT) {
  __shared__ __align__(16) float Wl[LL * WST];    // 66,560 B, pre-scaled by lw
  __shared__ __align__(16) float xs[K1_NR * DD];  //  4,096 B
  const int bx = blockIdx.x;
  const int b  = bx >> 7;              // NN/K1_NR == 128
  const int n0 = (bx & 127) * K1_NR;
  const int t  = threadIdx.x;
  const int l  = t & 63;
  const int r  = t >> 6;

  // stage W pre-scaled: 4096 float4 / 256 threads = 16 iters, fully coalesced
  const float4* Wp4 = (const float4*)Wp;
  #pragma unroll
  for (int it = 0; it < 16; ++it) {
    int idx = it * 256 + t;
    int ll  = idx >> 6;                 // W row (wave-uniform per iteration)
    int dq  = idx & 63;                 // float4 column
    float4 wv = Wp4[idx];
    float  w  = lw[ll];                 // L1-resident broadcast
    wv.x *= w; wv.y *= w; wv.z *= w; wv.w *= w;
    *(float4*)&Wl[ll * WST + dq * 4] = wv;
  }
  // stage K1_NR rows of x: 256 float4, one per thread, coalesced
  ((float4*)xs)[t] = ((const float4*)x)[((size_t)(b * NN + n0)) * (DD / 4) + t];
  __syncthreads();

  const float4* xrow = (const float4*)&xs[r * DD];   // wave-uniform -> broadcast
  const float4* wrow = (const float4*)&Wl[l * WST];  // per-lane row, padded stride
  float4 a = make_float4(0.f, 0.f, 0.f, 0.f);
  #pragma unroll 8
  for (int dd = 0; dd < 64; ++dd) {
    float4 xv = xrow[dd];
    float4 wv = wrow[dd];
    a.x += xv.x * wv.x;
    a.y += xv.y * wv.y;
    a.z += xv.z * wv.z;
    a.w += xv.w * wv.w;
  }
  xhatT[(size_t)b * (LL * NN) + (size_t)l * NN + (n0 + r)] = (a.x + a.y) + (a.z + a.w);
}

// ---------------------------------------------------------------------------
// k2: per (b, i-tile of IPB=8): dist -> leaky_relu -> rowmax -> adj*exp ->
//     rowsum -> divide -> +1e-10.  512 threads, thread = column j.
//
// ROUND-1 POST-MORTEM: xj[64] per-thread register array spilled to scratch
// (WRITE_SIZE 331 MB, FETCH 186 MB = scratch traffic; VALUBusy 3.6%).
// FIX: the whole per-batch xhatT slice is 64x512 floats = 128 KB, contiguous.
// Stage it ONCE per block into LDS with an identity float4 copy (perfectly
// coalesced), then the inner loop is pure LDS+VALU: xj_s[l][t] is a
// stride-1 conflict-free b32 read, xi is a same-address b128 broadcast.
// No per-thread arrays bigger than 8 -> no spill possible.
// LDS: 128 KB + 2 KB + 0.5 KB = 130.5 KB -> 1 block/CU (grid 256 = 1/CU).
// ---------------------------------------------------------------------------
__global__ __launch_bounds__(512) void k2_main(const float* __restrict__ xhatT,
                                               const float* __restrict__ adj,
                                               float* __restrict__ out) {
  __shared__ __align__(16) float xj_s[LL * NN];   // 131,072 B: full xj panel
  __shared__ __align__(16) float xi_s[LL * IPB];  //   2,048 B: [l][r], lw-scaled
  __shared__ float redm[IPB * 8];
  __shared__ float reds[IPB * 8];

  const int bx   = blockIdx.x;
  const int b    = bx >> 6;             // NN/IPB == 64
  const int i0   = (bx & 63) * IPB;
  const int t    = threadIdx.x;         // j
  const int wave = t >> 6;
  const int lane = t & 63;

  const float* xb = xhatT + (size_t)b * (LL * NN);

  // adj rows: the only true HBM read -- issue first so latency hides under
  // the xj staging copy.
  const float* adjb = adj + ((size_t)b * NN + i0) * NN;
  float adjv[IPB];
  #pragma unroll
  for (int r = 0; r < IPB; ++r) adjv[r] = adjb[(size_t)r * NN + t];

  // stage full xj panel: contiguous slice, identity float4 copy, coalesced
  {
    const float4* xb4 = (const float4*)xb;        // 8192 float4
    float4* xj4 = (float4*)xj_s;
    #pragma unroll
    for (int it = 0; it < 16; ++it)
      xj4[it * 512 + t] = xb4[it * 512 + t];
  }
  // xi tile: 512 threads stage 64 l x 8 r
  {
    int l = t >> 3, r = t & 7;
    xi_s[t] = xb[l * NN + i0 + r];
  }
  __syncthreads();

  float acc[IPB] = {0.f, 0.f, 0.f, 0.f, 0.f, 0.f, 0.f, 0.f};
  const float4* xi4 = (const float4*)xi_s;        // [l][2] float4
  #pragma unroll 16
  for (int l = 0; l < LL; ++l) {
    float  p  = xj_s[l * NN + t];                 // stride-1, conflict-free
    float4 a0 = xi4[l * 2 + 0];                   // broadcast b128
    float4 a1 = xi4[l * 2 + 1];                   // broadcast b128
    acc[0] += fabsf(a0.x - p);
    acc[1] += fabsf(a0.y - p);
    acc[2] += fabsf(a0.z - p);
    acc[3] += fabsf(a0.w - p);
    acc[4] += fabsf(a1.x - p);
    acc[5] += fabsf(a1.y - p);
    acc[6] += fabsf(a1.z - p);
    acc[7] += fabsf(a1.w - p);
  }

  // leaky_relu (dist >= 0 in practice, but stay faithful)
  #pragma unroll
  for (int r = 0; r < IPB; ++r) {
    float d = acc[r];
    acc[r] = d >= 0.f ? d : 0.01f * d;
  }

  // row max over 512 j: wave shfl reduce, then cross-wave via LDS
  #pragma unroll
  for (int r = 0; r < IPB; ++r) {
    float m = acc[r];
    #pragma unroll
    for (int off = 32; off > 0; off >>= 1)
      m = fmaxf(m, __shfl_xor(m, off, 64));
    if (lane == 0) redm[r * 8 + wave] = m;
  }
  __syncthreads();

  float e[IPB];
  #pragma unroll
  for (int r = 0; r < IPB; ++r) {
    float m = redm[r * 8 + 0];
    #pragma unroll
    for (int k = 1; k < 8; ++k) m = fmaxf(m, redm[r * 8 + k]);  // broadcast reads
    e[r] = adjv[r] * __expf(acc[r] - m);
  }

  // row sum
  #pragma unroll
  for (int r = 0; r < IPB; ++r) {
    float s = e[r];
    #pragma unroll
    for (int off = 32; off > 0; off >>= 1)
      s += __shfl_xor(s, off, 64);
    if (lane == 0) reds[r * 8 + wave] = s;
  }
  __syncthreads();

  float* outb = out + ((size_t)b * NN + i0) * NN;
  #pragma unroll
  for (int r = 0; r < IPB; ++r) {
    float s = reds[r * 8 + 0];
    #pragma unroll
    for (int k = 1; k < 8; ++k) s += reds[r * 8 + k];
    outb[(size_t)r * NN + t] = e[r] / s + 1e-10f;   // epsilon AFTER division
  }
}

extern "C" void kernel_launch(void* const* d_in, const int* in_sizes, int n_in,
                              void* d_out, int out_size, void* d_ws, size_t ws_size,
                              hipStream_t stream) {
  const float* x   = (const float*)d_in[0];   // [B,N,D]
  const float* adj = (const float*)d_in[1];   // [B,N,N]
  const float* Wp  = (const float*)d_in[2];   // [L,D]
  const float* lw  = (const float*)d_in[3];   // [L]
  float* out   = (float*)d_out;               // [B,N,N]
  float* xhatT = (float*)d_ws;                // B*L*N floats = 512 KiB

  hipLaunchKernelGGL(k1_proj, dim3(BB * NN / K1_NR), dim3(256), 0, stream,
                     x, Wp, lw, xhatT);
  hipLaunchKernelGGL(k2_main, dim3(BB * NN / IPB), dim3(512), 0, stream,
                     xhatT, adj, out);
}